// Round 4
// baseline (2097.736 us; speedup 1.0000x reference)
//
#include <hip/hip_runtime.h>
#include <stdint.h>

#define NB 4096
#define NS 512
#define NA 64
#define NH1 1024
#define NH2 512

typedef __attribute__((ext_vector_type(8))) short bf16x8;
typedef __attribute__((ext_vector_type(4))) float f32x4;

__device__ __forceinline__ unsigned short f2bf(float f) {
    union { float f; unsigned u; } v; v.f = f;
    return (unsigned short)((v.u + 0x8000u) >> 16);   // round-half-up bf16
}
__device__ __forceinline__ float bf2f(unsigned short h) {
    union { float f; unsigned u; } v; v.u = ((unsigned)h) << 16;
    return v.f;
}
__device__ __forceinline__ float bflo(unsigned u) {
    union { unsigned u; float f; } v; v.u = u << 16; return v.f;
}
__device__ __forceinline__ float bfhi(unsigned u) {
    union { unsigned u; float f; } v; v.u = u & 0xFFFF0000u; return v.f;
}
// truncating pack of two f32 -> bf16x2 (bias cancels in u/||u||): 1 v_perm
__device__ __forceinline__ unsigned packtrunc(float lo, float hi) {
    union { float f; unsigned u; } a, b; a.f = lo; b.f = hi;
    return __builtin_amdgcn_perm(b.u, a.u, 0x07060302u);
}
__device__ __forceinline__ void split2(float x, unsigned short& h, unsigned short& l) {
    unsigned short hh = f2bf(x);
    h = hh;
    l = f2bf(x - bf2f(hh));
}
__device__ __forceinline__ void async_copy16(const void* g, void* l) {
    __builtin_amdgcn_global_load_lds((const __attribute__((address_space(1))) void*)g,
                                     (__attribute__((address_space(3))) void*)l, 16, 0, 0);
}

// ---------------- P0: nb[b] = sqrt(||s_b||^2 + 1) + 1e-8 ----------------
__global__ void knorm(const float* __restrict__ S, float* __restrict__ nb) {
    int b = blockIdx.x; int l = threadIdx.x; // one wave
    const float* row = S + b * NS;
    float s = 0.f;
    for (int k = l; k < NS; k += 64) { float v = row[k]; s = fmaf(v, v, s); }
    for (int off = 32; off; off >>= 1) s += __shfl_down(s, off, 64);
    if (l == 0) nb[b] = sqrtf(s + 1.0f) + 1e-8f;
}

// ---------------- P1: W2f (DMA-frag-packed, 2-way-swizzled) + caT2 ----------------
// W2f short idx = (((cb*32+kc)*16 + c)*64 + l)*8 + j :
//   n_loc = c*16 + (l>>2); g = (l&3) ^ ((n_loc>>1)&3);
//   value = W2[cb*256 + n_loc][kc*32 + g*8 + j]
// caT2[at][kc][a_loc][kk] = W1[(kc*32+kk)*576 + 512 + at*16 + a_loc]
__global__ void kprep(const float* __restrict__ W1, const float* __restrict__ W2,
                      unsigned short* __restrict__ W2f, unsigned short* __restrict__ caT2) {
    int i = blockIdx.x * 256 + threadIdx.x;
    if (i < 524288) {
        int j = i & 7; int l = (i >> 3) & 63; int c = (i >> 9) & 15;
        int kc = (i >> 13) & 31; int cbb = i >> 18;
        int n_loc = c * 16 + (l >> 2);
        int g = (l & 3) ^ ((n_loc >> 1) & 3);
        int n = cbb * 256 + n_loc;
        int k = kc * 32 + g * 8 + j;
        W2f[i] = f2bf(W2[(size_t)n * NH1 + k]);
    } else {
        int j2 = i - 524288;                 // 65536 entries
        int kk = j2 & 31; int a_loc = (j2 >> 5) & 15;
        int kc = (j2 >> 9) & 31; int att = j2 >> 14;
        int o = kc * 32 + kk;
        caT2[j2] = f2bf(W1[(size_t)o * 576 + 512 + att * 16 + a_loc]);
    }
}

// ---------------- P2: Gt'[kc][b][32k] bf16 = s@W1s^T + b1*nb  (split-bf16, 3 GEMMs) ----
__global__ __launch_bounds__(256) void kgemm1(
        const float* __restrict__ Sm, const float* __restrict__ W1,
        const float* __restrict__ b1, const float* __restrict__ nb,
        unsigned short* __restrict__ Gt) {
    const int m0 = (blockIdx.x >> 3) * 128;
    const int n0 = (blockIdx.x & 7) * 128;
    __shared__ unsigned short Ah[128][40], Al[128][40], Bh[128][40], Bl[128][40];
    int t = threadIdx.x;
    int lane = t & 63, wave = t >> 6;
    int wr = wave >> 1, wc = wave & 1;
    int qd = lane >> 4, cl = lane & 15;
    int r = t >> 1, seg = t & 1;
    f32x4 acc[4][4] = {};

    for (int k0 = 0; k0 < 512; k0 += 32) {
        {
            const float4* as4 = (const float4*)(Sm + (size_t)(m0 + r) * NS + k0 + seg * 16);
            const float4* bs4 = (const float4*)(W1 + (size_t)(n0 + r) * 576 + k0 + seg * 16);
            unsigned* ah = (unsigned*)&Ah[r][seg * 16];
            unsigned* al = (unsigned*)&Al[r][seg * 16];
            unsigned* bh = (unsigned*)&Bh[r][seg * 16];
            unsigned* bl = (unsigned*)&Bl[r][seg * 16];
#pragma unroll
            for (int v = 0; v < 4; v++) {
                float4 fa = as4[v];
                unsigned short h0,h1,h2,h3,l0,l1,l2,l3;
                split2(fa.x,h0,l0); split2(fa.y,h1,l1); split2(fa.z,h2,l2); split2(fa.w,h3,l3);
                ah[v*2]   = (unsigned)h0 | ((unsigned)h1 << 16);
                ah[v*2+1] = (unsigned)h2 | ((unsigned)h3 << 16);
                al[v*2]   = (unsigned)l0 | ((unsigned)l1 << 16);
                al[v*2+1] = (unsigned)l2 | ((unsigned)l3 << 16);
                float4 fb = bs4[v];
                split2(fb.x,h0,l0); split2(fb.y,h1,l1); split2(fb.z,h2,l2); split2(fb.w,h3,l3);
                bh[v*2]   = (unsigned)h0 | ((unsigned)h1 << 16);
                bh[v*2+1] = (unsigned)h2 | ((unsigned)h3 << 16);
                bl[v*2]   = (unsigned)l0 | ((unsigned)l1 << 16);
                bl[v*2+1] = (unsigned)l2 | ((unsigned)l3 << 16);
            }
        }
        __syncthreads();
        bf16x8 a_h[4], a_l[4], b_h[4], b_l[4];
#pragma unroll
        for (int mt = 0; mt < 4; mt++) {
            a_h[mt] = *(const bf16x8*)&Ah[wr*64 + mt*16 + cl][qd*8];
            a_l[mt] = *(const bf16x8*)&Al[wr*64 + mt*16 + cl][qd*8];
        }
#pragma unroll
        for (int nt = 0; nt < 4; nt++) {
            b_h[nt] = *(const bf16x8*)&Bh[wc*64 + nt*16 + cl][qd*8];
            b_l[nt] = *(const bf16x8*)&Bl[wc*64 + nt*16 + cl][qd*8];
        }
#pragma unroll
        for (int mt = 0; mt < 4; mt++)
#pragma unroll
            for (int nt = 0; nt < 4; nt++) {
                acc[mt][nt] = __builtin_amdgcn_mfma_f32_16x16x32_bf16(a_h[mt], b_h[nt], acc[mt][nt], 0, 0, 0);
                acc[mt][nt] = __builtin_amdgcn_mfma_f32_16x16x32_bf16(a_h[mt], b_l[nt], acc[mt][nt], 0, 0, 0);
                acc[mt][nt] = __builtin_amdgcn_mfma_f32_16x16x32_bf16(a_l[mt], b_h[nt], acc[mt][nt], 0, 0, 0);
            }
        __syncthreads();
    }
#pragma unroll
    for (int mt = 0; mt < 4; mt++)
#pragma unroll
        for (int i = 0; i < 4; i++) {
            int m = m0 + wr*64 + mt*16 + qd*4 + i;
            float nbv = nb[m];
#pragma unroll
            for (int nt = 0; nt < 4; nt++) {
                int n = n0 + wc*64 + nt*16 + cl;
                float val = fmaf(b1[n], nbv, acc[mt][nt][i]);
                Gt[((size_t)(n >> 5) * NB + m) * 32 + (n & 31)] = f2bf(val);
            }
        }
}

// ---------------- Main: rows 128 (16a x 8b) x cols 256, K=1024, Kc=32 ----------------
// grid 4096 = (512 bt x 4 at) x 2 cb; 4 waves 2Mx2N, wave tile 64x128.
// u = relu(G' + ca); acc = u @ W2^T; sq via Gram-MFMA; z = acc/||u|| + b2.
__global__ __launch_bounds__(256, 2) void kmain(
        const unsigned short* __restrict__ Gt,    // [32][4096][32]
        const unsigned short* __restrict__ caT2,  // [4][32][16][32]
        const unsigned short* __restrict__ W2f,   // frag-packed, swizzled
        const float* __restrict__ nb,
        const float* __restrict__ b2, const float* __restrict__ Wq,
        const float* __restrict__ bq, float* __restrict__ out) {
    int bid = blockIdx.x;
    int cb = bid & 1;
    int rt = bid >> 1;
    int at = rt & 3;
    int bt = rt >> 2;

    __shared__ __align__(16) unsigned short Bs[2][8192];   // 2 x 16 KB B tiles
    __shared__ __align__(16) unsigned short Afr[4096];     // 8 KB A-frag buffer
    __shared__ float invnh[128];
    __shared__ float qred[128][2];

    int t = threadIdx.x;
    int lane = t & 63, w = t >> 6;
    int wr = w >> 1, wc = w & 1;
    int l15 = lane & 15, l4 = lane >> 4;
    int bl = lane & 7;

    // producer role: this wave computes frags mt0, mt0+1 for row-group wr
    int mt0 = 2 * wc;
    int aloc0 = wr * 8 + mt0 * 2 + (l15 >> 3);

    // global source pointers (advanced by kc each iter)
    const unsigned short* gG = Gt + ((size_t)(bt * 8 + bl)) * 32 + l4 * 8;
    const unsigned short* gC0 = caT2 + (((size_t)at * 32) * 16 + aloc0) * 32 + l4 * 8;
    const unsigned short* gC1 = gC0 + 2 * 32;
    const char* gB = (const char*)W2f + ((size_t)cb << 19);   // cb * 32 tiles * 16 KB

    f32x4 acc[4][8] = {};
    f32x4 accsq0 = {}, accsq1 = {};

    // hoisted LDS addresses
    int sw = ((wc * 128 + l15) >> 1) & 3;
    const unsigned short* bbase0 = Bs[0] + (wc * 128 + l15) * 32 + ((l4 ^ sw) << 3);
    const unsigned short* bbase1 = Bs[1] + (wc * 128 + l15) * 32 + ((l4 ^ sw) << 3);
    unsigned short* afw0 = Afr + (wr * 4 + mt0) * 512 + lane * 8;       // own frag writes
    const unsigned short* afr0 = Afr + (wr * 4 + 2 * (1 - wc)) * 512 + lane * 8;  // partner reads

    // register prefetch (iteration 0)
    bf16x8 g_v = *(const bf16x8*)gG;
    bf16x8 c_v0 = *(const bf16x8*)gC0;
    bf16x8 c_v1 = *(const bf16x8*)gC1;

    { // fill(0) into slot 0
        const char* gs = gB + (w * 4) * 1024 + (lane << 4);
        char* ld = (char*)Bs[0] + (w * 4) * 1024 + (lane << 4);
#pragma unroll
        for (int i2 = 0; i2 < 4; i2++)
            async_copy16(gs + i2 * 1024, ld + i2 * 1024);
    }

    for (int it = 0; it < 32; ++it) {
        __syncthreads();   // T: drains fill(it) + g/ca loads (issued one iter ago)

        // ---- A-gen: u = relu(G' + ca), truncate-pack; 16 el/lane ----
        bf16x8 fr0v, fr1v;
        {
            const unsigned* gd = (const unsigned*)&g_v;
            const unsigned* cd0 = (const unsigned*)&c_v0;
            const unsigned* cd1 = (const unsigned*)&c_v1;
            unsigned* f0 = (unsigned*)&fr0v;
            unsigned* f1 = (unsigned*)&fr1v;
#pragma unroll
            for (int p = 0; p < 4; p++) {
                float g0 = bflo(gd[p]), g1 = bfhi(gd[p]);
                unsigned cu0 = cd0[p], cu1 = cd1[p];
                float u00 = fmaxf(g0 + bflo(cu0), 0.f);
                float u01 = fmaxf(g1 + bfhi(cu0), 0.f);
                float u10 = fmaxf(g0 + bflo(cu1), 0.f);
                float u11 = fmaxf(g1 + bfhi(cu1), 0.f);
                f0[p] = packtrunc(u00, u01);
                f1[p] = packtrunc(u10, u11);
            }
        }
        // Gram MFMA accumulates Sum(u^2) on the diagonal
        accsq0 = __builtin_amdgcn_mfma_f32_16x16x32_bf16(fr0v, fr0v, accsq0, 0, 0, 0);
        accsq1 = __builtin_amdgcn_mfma_f32_16x16x32_bf16(fr1v, fr1v, accsq1, 0, 0, 0);
        *(bf16x8*)afw0 = fr0v;
        *(bf16x8*)(afw0 + 512) = fr1v;

        __syncthreads();   // U: frag writes visible; no vmem issued since T

        if (it < 31) {     // issue next fill + next G/ca register loads
            int s2 = (it + 1) & 1;
            const char* gs = gB + (size_t)(it + 1) * 16384 + (w * 4) * 1024 + (lane << 4);
            char* ld = (char*)Bs[s2] + (w * 4) * 1024 + (lane << 4);
#pragma unroll
            for (int i2 = 0; i2 < 4; i2++)
                async_copy16(gs + i2 * 1024, ld + i2 * 1024);
            gG += (size_t)NB * 32;
            gC0 += 512;
            gC1 += 512;
            g_v = *(const bf16x8*)gG;
            c_v0 = *(const bf16x8*)gC0;
            c_v1 = *(const bf16x8*)gC1;
        }

        // ---- MFMA phase ----
        bf16x8 af[4];
        af[mt0] = fr0v;
        af[mt0 + 1] = fr1v;
        af[2 * (1 - wc)] = *(const bf16x8*)afr0;
        af[2 * (1 - wc) + 1] = *(const bf16x8*)(afr0 + 512);

        const unsigned short* bb = (it & 1) ? bbase1 : bbase0;
        bf16x8 bfr[8];
#pragma unroll
        for (int nt = 0; nt < 8; nt++)
            bfr[nt] = *(const bf16x8*)(bb + nt * 512);
#pragma unroll
        for (int mt = 0; mt < 4; mt++)
#pragma unroll
            for (int nt = 0; nt < 8; nt++)
                acc[mt][nt] = __builtin_amdgcn_mfma_f32_16x16x32_bf16(af[mt], bfr[nt], acc[mt][nt], 0, 0, 0);
    }

    // ---- diag extract -> invnh (producer rows) ----
    {
        float nbv = nb[bt * 8 + (l15 & 7)];
        bool own = (l4 == (l15 >> 2));
        float s0 = (l15 & 1) ? ((l15 & 2) ? accsq0.w : accsq0.y)
                             : ((l15 & 2) ? accsq0.z : accsq0.x);
        float s1 = (l15 & 1) ? ((l15 & 2) ? accsq1.w : accsq1.y)
                             : ((l15 & 2) ? accsq1.z : accsq1.x);
        if (own) {
            invnh[wr * 64 + mt0 * 16 + l15] = 1.0f / (sqrtf(s0) + 1e-8f * nbv);
            invnh[wr * 64 + (mt0 + 1) * 16 + l15] = 1.0f / (sqrtf(s1) + 1e-8f * nbv);
        }
    }
    __syncthreads();

    // ---- epilogue: z = acc*invnh + b2; relu; q = sum(Wq*z) over cols ----
    float wqv[8], b2v[8];
#pragma unroll
    for (int nt = 0; nt < 8; nt++) {
        int o = cb * 256 + wc * 128 + nt * 16 + l15;
        wqv[nt] = Wq[o]; b2v[nt] = b2[o];
    }
#pragma unroll
    for (int mt = 0; mt < 4; mt++) {
#pragma unroll
        for (int i = 0; i < 4; i++) {
            int R = wr * 64 + mt * 16 + l4 * 4 + i;
            float inv = invnh[R];
            float qp = 0.f;
#pragma unroll
            for (int nt = 0; nt < 8; nt++) {
                float z = fmaf(acc[mt][nt][i], inv, b2v[nt]);
                z = fmaxf(z, 0.f);
                qp = fmaf(z, wqv[nt], qp);
            }
            qp += __shfl_xor(qp, 1, 64);
            qp += __shfl_xor(qp, 2, 64);
            qp += __shfl_xor(qp, 4, 64);
            qp += __shfl_xor(qp, 8, 64);
            if (l15 == 0) qred[R][wc] = qp;
        }
    }
    __syncthreads();
    if (t < 128) {
        float qv = qred[t][0] + qred[t][1];
        if (cb == 0) qv += bq[0];
        int aa = at * 16 + (t >> 3);
        int bb2 = bt * 8 + (t & 7);
        atomicAdd(out + (size_t)bb2 * NA + aa, qv);
    }
}

extern "C" void kernel_launch(void* const* d_in, const int* in_sizes, int n_in,
                              void* d_out, int out_size, void* d_ws, size_t ws_size,
                              hipStream_t stream) {
    const float* states = (const float*)d_in[0];
    const float* W1     = (const float*)d_in[1];
    const float* b1     = (const float*)d_in[2];
    const float* W2     = (const float*)d_in[3];
    const float* b2     = (const float*)d_in[4];
    const float* Wq     = (const float*)d_in[5];
    const float* bq     = (const float*)d_in[6];
    float* out = (float*)d_out;

    char* ws = (char*)d_ws;
    unsigned short* Gt   = (unsigned short*)ws;                              // 8 MB
    unsigned short* W2f  = (unsigned short*)(ws + (8u << 20));               // 1 MB
    unsigned short* caT2 = (unsigned short*)(ws + (9u << 20));               // 128 KB
    float*          nbp  = (float*)(ws + (9u << 20) + (128u << 10));         // 16 KB

    hipMemsetAsync(d_out, 0, (size_t)out_size * sizeof(float), stream);
    knorm<<<NB, 64, 0, stream>>>(states, nbp);
    kprep<<<2304, 256, 0, stream>>>(W1, W2, W2f, caT2);
    kgemm1<<<256, 256, 0, stream>>>(states, W1, b1, nbp, Gt);
    kmain<<<4096, 256, 0, stream>>>(Gt, caT2, W2f, nbp, b2, Wq, bq, out);
}

// Round 6
// 401.318 us; speedup vs baseline: 5.2271x; 5.2271x over previous
//
#include <hip/hip_runtime.h>
#include <stdint.h>

#define NB 4096
#define NS 512
#define NA 64
#define NH1 1024
#define NH2 512

typedef __attribute__((ext_vector_type(8))) short bf16x8;
typedef __attribute__((ext_vector_type(4))) float f32x4;

__device__ __forceinline__ unsigned short f2bf(float f) {
    union { float f; unsigned u; } v; v.f = f;
    return (unsigned short)((v.u + 0x8000u) >> 16);   // round-half-up bf16
}
__device__ __forceinline__ float bf2f(unsigned short h) {
    union { float f; unsigned u; } v; v.u = ((unsigned)h) << 16;
    return v.f;
}
__device__ __forceinline__ float bflo(unsigned u) {
    union { unsigned u; float f; } v; v.u = u << 16; return v.f;
}
__device__ __forceinline__ float bfhi(unsigned u) {
    union { unsigned u; float f; } v; v.u = u & 0xFFFF0000u; return v.f;
}
// truncating pack of two f32 -> bf16x2 (bias cancels in u/||u||): 1 v_perm
__device__ __forceinline__ unsigned packtrunc(float lo, float hi) {
    union { float f; unsigned u; } a, b; a.f = lo; b.f = hi;
    return __builtin_amdgcn_perm(b.u, a.u, 0x07060302u);
}
__device__ __forceinline__ void split2(float x, unsigned short& h, unsigned short& l) {
    unsigned short hh = f2bf(x);
    h = hh;
    l = f2bf(x - bf2f(hh));
}
__device__ __forceinline__ void async_copy16(const void* g, void* l) {
    __builtin_amdgcn_global_load_lds((const __attribute__((address_space(1))) void*)g,
                                     (__attribute__((address_space(3))) void*)l, 16, 0, 0);
}

// ---------------- P0: nb[b] = sqrt(||s_b||^2 + 1) + 1e-8 ----------------
__global__ void knorm(const float* __restrict__ S, float* __restrict__ nb) {
    int b = blockIdx.x; int l = threadIdx.x; // one wave
    const float* row = S + b * NS;
    float s = 0.f;
    for (int k = l; k < NS; k += 64) { float v = row[k]; s = fmaf(v, v, s); }
    for (int off = 32; off; off >>= 1) s += __shfl_down(s, off, 64);
    if (l == 0) nb[b] = sqrtf(s + 1.0f) + 1e-8f;
}

// ---------------- P1: W2f (DMA-frag-packed per-kc tiles, swizzled) + caT2 ----------------
// W2f short idx = ((kc*32 + c)*64 + l)*8 + j :
//   n = c*16 + (l>>2);  g = (l&3) ^ ((n>>1)&3);  value = W2[n][kc*32 + g*8 + j]
// Per-kc tile = 32*64*8 shorts = 32 KB  (byte stride kc<<15 !)
// caT2[at][kc][a_loc][kk] = W1[(kc*32+kk)*576 + 512 + at*16 + a_loc]
__global__ void kprep(const float* __restrict__ W1, const float* __restrict__ W2,
                      unsigned short* __restrict__ W2f, unsigned short* __restrict__ caT2) {
    int i = blockIdx.x * 256 + threadIdx.x;
    if (i < 524288) {
        int j = i & 7; int l = (i >> 3) & 63; int c = (i >> 9) & 31; int kc = i >> 14;
        int n = c * 16 + (l >> 2);
        int g = (l & 3) ^ ((n >> 1) & 3);
        int k = kc * 32 + g * 8 + j;
        W2f[i] = f2bf(W2[(size_t)n * NH1 + k]);
    } else {
        int j2 = i - 524288;                 // 65536 entries
        int kk = j2 & 31; int a_loc = (j2 >> 5) & 15;
        int kc = (j2 >> 9) & 31; int att = j2 >> 14;
        int o = kc * 32 + kk;
        caT2[j2] = f2bf(W1[(size_t)o * 576 + 512 + att * 16 + a_loc]);
    }
}

// ---------------- P2: Gt'[kc][b][32k] bf16 = s@W1s^T + b1*nb  (split-bf16, 3 GEMMs) ----
__global__ __launch_bounds__(256) void kgemm1(
        const float* __restrict__ Sm, const float* __restrict__ W1,
        const float* __restrict__ b1, const float* __restrict__ nb,
        unsigned short* __restrict__ Gt) {
    const int m0 = (blockIdx.x >> 3) * 128;
    const int n0 = (blockIdx.x & 7) * 128;
    __shared__ unsigned short Ah[128][40], Al[128][40], Bh[128][40], Bl[128][40];
    int t = threadIdx.x;
    int lane = t & 63, wave = t >> 6;
    int wr = wave >> 1, wc = wave & 1;
    int qd = lane >> 4, cl = lane & 15;
    int r = t >> 1, seg = t & 1;
    f32x4 acc[4][4] = {};

    for (int k0 = 0; k0 < 512; k0 += 32) {
        {
            const float4* as4 = (const float4*)(Sm + (size_t)(m0 + r) * NS + k0 + seg * 16);
            const float4* bs4 = (const float4*)(W1 + (size_t)(n0 + r) * 576 + k0 + seg * 16);
            unsigned* ah = (unsigned*)&Ah[r][seg * 16];
            unsigned* al = (unsigned*)&Al[r][seg * 16];
            unsigned* bh = (unsigned*)&Bh[r][seg * 16];
            unsigned* bl = (unsigned*)&Bl[r][seg * 16];
#pragma unroll
            for (int v = 0; v < 4; v++) {
                float4 fa = as4[v];
                unsigned short h0,h1,h2,h3,l0,l1,l2,l3;
                split2(fa.x,h0,l0); split2(fa.y,h1,l1); split2(fa.z,h2,l2); split2(fa.w,h3,l3);
                ah[v*2]   = (unsigned)h0 | ((unsigned)h1 << 16);
                ah[v*2+1] = (unsigned)h2 | ((unsigned)h3 << 16);
                al[v*2]   = (unsigned)l0 | ((unsigned)l1 << 16);
                al[v*2+1] = (unsigned)l2 | ((unsigned)l3 << 16);
                float4 fb = bs4[v];
                split2(fb.x,h0,l0); split2(fb.y,h1,l1); split2(fb.z,h2,l2); split2(fb.w,h3,l3);
                bh[v*2]   = (unsigned)h0 | ((unsigned)h1 << 16);
                bh[v*2+1] = (unsigned)h2 | ((unsigned)h3 << 16);
                bl[v*2]   = (unsigned)l0 | ((unsigned)l1 << 16);
                bl[v*2+1] = (unsigned)l2 | ((unsigned)l3 << 16);
            }
        }
        __syncthreads();
        bf16x8 a_h[4], a_l[4], b_h[4], b_l[4];
#pragma unroll
        for (int mt = 0; mt < 4; mt++) {
            a_h[mt] = *(const bf16x8*)&Ah[wr*64 + mt*16 + cl][qd*8];
            a_l[mt] = *(const bf16x8*)&Al[wr*64 + mt*16 + cl][qd*8];
        }
#pragma unroll
        for (int nt = 0; nt < 4; nt++) {
            b_h[nt] = *(const bf16x8*)&Bh[wc*64 + nt*16 + cl][qd*8];
            b_l[nt] = *(const bf16x8*)&Bl[wc*64 + nt*16 + cl][qd*8];
        }
#pragma unroll
        for (int mt = 0; mt < 4; mt++)
#pragma unroll
            for (int nt = 0; nt < 4; nt++) {
                acc[mt][nt] = __builtin_amdgcn_mfma_f32_16x16x32_bf16(a_h[mt], b_h[nt], acc[mt][nt], 0, 0, 0);
                acc[mt][nt] = __builtin_amdgcn_mfma_f32_16x16x32_bf16(a_h[mt], b_l[nt], acc[mt][nt], 0, 0, 0);
                acc[mt][nt] = __builtin_amdgcn_mfma_f32_16x16x32_bf16(a_l[mt], b_h[nt], acc[mt][nt], 0, 0, 0);
            }
        __syncthreads();
    }
#pragma unroll
    for (int mt = 0; mt < 4; mt++)
#pragma unroll
        for (int i = 0; i < 4; i++) {
            int m = m0 + wr*64 + mt*16 + qd*4 + i;
            float nbv = nb[m];
#pragma unroll
            for (int nt = 0; nt < 4; nt++) {
                int n = n0 + wc*64 + nt*16 + cl;
                float val = fmaf(b1[n], nbv, acc[mt][nt][i]);
                Gt[((size_t)(n >> 5) * NB + m) * 32 + (n & 31)] = f2bf(val);
            }
        }
}

// ---------------- Main: 512 thr, 128 rows (16a x 8b) x 512 cols, K=1024, Kc=32 ----------
// grid 2048 = 512 bt x 4 at. 8 waves: wr = w>>2 (row half), wc = w&3 (col quarter).
// 1-barrier dbuf: A-gen(it+1)/DMA-B(it+1) overlap MFMA(it). Redundancy-1 A-gen.
__global__ __launch_bounds__(512, 2) void kmain(
        const unsigned short* __restrict__ Gt,    // [32][4096][32]
        const unsigned short* __restrict__ caT2,  // [4][32][16][32]
        const unsigned short* __restrict__ W2f,   // per-kc frag-packed tiles (32 KB each)
        const float* __restrict__ nb,
        const float* __restrict__ b2, const float* __restrict__ Wq,
        const float* __restrict__ bq, float* __restrict__ out) {
    int bid = blockIdx.x;
    int at = bid & 3;
    int bt = bid >> 2;

    __shared__ __align__(16) unsigned short As[2][128][40];  // 2 x 10 KB, pad +8
    __shared__ __align__(16) unsigned short Bs[2][16384];    // 2 x 32 KB swizzled
    __shared__ float invnh[128];
    __shared__ float qred[128][4];

    int t = threadIdx.x;
    int lane = t & 63, w = t >> 6;
    int wr = w >> 2, wc = w & 3;
    int l15 = lane & 15, l4 = lane >> 4;

    // A-gen role: thread owns row (t>>2), k-octet (t&3); 8 elements/iter
    int row = t >> 2, kd = t & 3;
    int ab = row >> 3, bb = row & 7;
    const unsigned short* gG = Gt + ((size_t)(bt * 8 + bb)) * 32 + kd * 8;
    const unsigned short* gC = caT2 + (size_t)at * 16384 + ab * 32 + kd * 8;

    float sq = 0.f;
    f32x4 acc[4][8] = {};
    bf16x8 g_v, c_v;

    auto fillB = [&](int kc, int s) {
        // per-kc tile stride = 32 KB  (kc << 15; R5's <<16 read past W2f -> NaN bf16 patterns)
        const char* gs = (const char*)W2f + ((size_t)kc << 15) + w * 1024 + (lane << 4);
        char* ld = (char*)Bs[s] + w * 1024 + (lane << 4);
        async_copy16(gs, ld);
        async_copy16(gs + 8192, ld + 8192);
        async_copy16(gs + 16384, ld + 16384);
        async_copy16(gs + 24576, ld + 24576);
    };
    auto agen = [&](int s) {
        const unsigned* gd = (const unsigned*)&g_v;
        const unsigned* cd = (const unsigned*)&c_v;
        unsigned ow[4];
#pragma unroll
        for (int p = 0; p < 4; p++) {
            float u0 = fmaxf(bflo(gd[p]) + bflo(cd[p]), 0.f);
            float u1 = fmaxf(bfhi(gd[p]) + bfhi(cd[p]), 0.f);
            sq = fmaf(u0, u0, sq);
            sq = fmaf(u1, u1, sq);
            ow[p] = packtrunc(u0, u1);
        }
        *(bf16x8*)&As[s][row][kd * 8] = *(bf16x8*)ow;
    };

    // prologue: gen(0), fill B(0), prefetch g/c(1)
    g_v = *(const bf16x8*)gG;
    c_v = *(const bf16x8*)gC;
    agen(0);
    fillB(0, 0);
    gG += (size_t)NB * 32;
    gC += 512;
    g_v = *(const bf16x8*)gG;
    c_v = *(const bf16x8*)gC;

    // hoisted B frag base (swizzle (l15>>1)&3 is nt-independent)
    const int boff = (wc * 128 + l15) * 32 + ((l4 ^ ((l15 >> 1) & 3)) << 3);

    for (int it = 0; it < 32; ++it) {
        int s = it & 1;
        __syncthreads();   // drains fill(it) + g/c regs (issued ~1 iter ago)

        if (it < 31) {
            agen(s ^ 1);            // u(it+1) -> other A slot (reads g_v/c_v)
            fillB(it + 1, s ^ 1);   // B(it+1) -> other B slot (in flight until next barrier)
            if (it < 30) {
                gG += (size_t)NB * 32;
                gC += 512;
                g_v = *(const bf16x8*)gG;   // for gen(it+2), lands before next barrier
                c_v = *(const bf16x8*)gC;
            }
        }

        // ---- MFMA(it): wave tile 64 rows x 128 cols ----
        bf16x8 af[4], bfr[8];
#pragma unroll
        for (int mt = 0; mt < 4; mt++)
            af[mt] = *(const bf16x8*)&As[s][wr * 64 + mt * 16 + l15][l4 * 8];
        const unsigned short* bb2 = Bs[s] + boff;
#pragma unroll
        for (int nt = 0; nt < 8; nt++)
            bfr[nt] = *(const bf16x8*)(bb2 + nt * 512);
#pragma unroll
        for (int mt = 0; mt < 4; mt++)
#pragma unroll
            for (int nt = 0; nt < 8; nt++)
                acc[mt][nt] = __builtin_amdgcn_mfma_f32_16x16x32_bf16(af[mt], bfr[nt], acc[mt][nt], 0, 0, 0);
    }

    // ---- ||u|| per row: reduce over 4 kd threads (consecutive lanes) ----
    sq += __shfl_xor(sq, 1, 64);
    sq += __shfl_xor(sq, 2, 64);
    if (kd == 0) invnh[row] = 1.0f / (sqrtf(sq) + 1e-8f * nb[bt * 8 + bb]);
    __syncthreads();

    // ---- epilogue: z = acc*invnh + b2; relu; q = sum(Wq*z) ----
    float wqv[8], b2v[8];
#pragma unroll
    for (int nt = 0; nt < 8; nt++) {
        int o = wc * 128 + nt * 16 + l15;
        wqv[nt] = Wq[o]; b2v[nt] = b2[o];
    }
#pragma unroll
    for (int mt = 0; mt < 4; mt++) {
#pragma unroll
        for (int i = 0; i < 4; i++) {
            int R = wr * 64 + mt * 16 + l4 * 4 + i;
            float inv = invnh[R];
            float qp = 0.f;
#pragma unroll
            for (int nt = 0; nt < 8; nt++) {
                float z = fmaf(acc[mt][nt][i], inv, b2v[nt]);
                z = fmaxf(z, 0.f);
                qp = fmaf(z, wqv[nt], qp);
            }
            qp += __shfl_xor(qp, 1, 64);
            qp += __shfl_xor(qp, 2, 64);
            qp += __shfl_xor(qp, 4, 64);
            qp += __shfl_xor(qp, 8, 64);
            if (l15 == 0) qred[R][wc] = qp;
        }
    }
    __syncthreads();
    if (t < 128) {
        float qv = qred[t][0] + qred[t][1] + qred[t][2] + qred[t][3] + bq[0];
        int aa = at * 16 + (t >> 3);
        int bo = bt * 8 + (t & 7);
        out[(size_t)bo * NA + aa] = qv;
    }
}

extern "C" void kernel_launch(void* const* d_in, const int* in_sizes, int n_in,
                              void* d_out, int out_size, void* d_ws, size_t ws_size,
                              hipStream_t stream) {
    const float* states = (const float*)d_in[0];
    const float* W1     = (const float*)d_in[1];
    const float* b1     = (const float*)d_in[2];
    const float* W2     = (const float*)d_in[3];
    const float* b2     = (const float*)d_in[4];
    const float* Wq     = (const float*)d_in[5];
    const float* bq     = (const float*)d_in[6];
    float* out = (float*)d_out;

    char* ws = (char*)d_ws;
    unsigned short* Gt   = (unsigned short*)ws;                              // 8 MB
    unsigned short* W2f  = (unsigned short*)(ws + (8u << 20));               // 1 MB
    unsigned short* caT2 = (unsigned short*)(ws + (9u << 20));               // 128 KB
    float*          nbp  = (float*)(ws + (9u << 20) + (128u << 10));         // 16 KB

    knorm<<<NB, 64, 0, stream>>>(states, nbp);
    kprep<<<2304, 256, 0, stream>>>(W1, W2, W2f, caT2);
    kgemm1<<<256, 256, 0, stream>>>(states, W1, b1, nbp, Gt);
    kmain<<<2048, 512, 0, stream>>>(Gt, caT2, W2f, nbp, b2, Wq, bq, out);
}